// Round 2
// baseline (1425.706 us; speedup 1.0000x reference)
//
#include <hip/hip_runtime.h>
#include <hip/hip_bf16.h>

// All input/output buffers are FP32 (values are bf16-quantized by the harness,
// but the buffers are float32 per the reference dtypes).

// Workspace layout (float element offsets). Total = 12,833,792 floats = 51.3 MB.
#define XC_OFF   0          // xc  [2][64][16][16][16][16] fp32 = 8,388,608
#define Y1_OFF   8388608    // Y1  [2][32][65536]          fp32 = 4,194,304
#define W1R_OFF  12582912   // w1 reordered [cog8][tap81][ci64][4] = 165,888
#define W2R_OFF  12748800   // w2 reordered [cog8][tap81][ci32][4] =  82,944
#define W3R_OFF  12831744   // w3 reordered [cog8][ci64][4]        =   2,048

// ---------------------------------------------------------------------------
// Kernel 0: reorder weights to [cog][tap][ci][4co] so the conv inner loop
// does one float4 (uniform-address -> scalar) load per 4 FMAs.
// ---------------------------------------------------------------------------
__global__ void reorder_w(const float* __restrict__ w1, const float* __restrict__ w2,
                          const float* __restrict__ w3, float* __restrict__ ws) {
    int idx = blockIdx.x * 256 + threadIdx.x;
    float* w1r = ws + W1R_OFF;
    float* w2r = ws + W2R_OFF;
    float* w3r = ws + W3R_OFF;
    if (idx < 165888) {
        int r = idx & 3, ci = (idx >> 2) & 63, rest = idx >> 8;
        int tap = rest % 81, cog = rest / 81;
        w1r[idx] = w1[((cog * 4 + r) * 64 + ci) * 81 + tap];
    } else if (idx < 165888 + 82944) {
        int i2 = idx - 165888;
        int r = i2 & 3, ci = (i2 >> 2) & 31, rest = i2 >> 7;
        int tap = rest % 81, cog = rest / 81;
        w2r[i2] = w2[((cog * 4 + r) * 32 + ci) * 81 + tap];
    } else if (idx < 165888 + 82944 + 2048) {
        int i3 = idx - (165888 + 82944);
        int r = i3 & 3, ci = (i3 >> 2) & 63, cog = i3 >> 8;
        w3r[i3] = w3[(cog * 4 + r) * 64 + ci];
    }
}

// ---------------------------------------------------------------------------
// Kernel 1: fused tconv4d(k=2,s=2) + concat -> xc fp32 [2][64][16^4].
// Channels 0..31 = x2 copy; channels 32..63 = upsample of x1.
// ---------------------------------------------------------------------------
__global__ void up_concat(const float* __restrict__ x1, const float* __restrict__ x2,
                          const float* __restrict__ up_w, const float* __restrict__ up_b,
                          float* __restrict__ xc) {
    int idx = blockIdx.x * 256 + threadIdx.x;   // 2*64*65536 threads
    int pos = idx & 65535;
    int c = (idx >> 16) & 63;
    int b = idx >> 22;
    float v;
    if (c < 32) {
        v = x2[((b * 32 + c) << 16) + pos];
    } else {
        int co = c - 32;
        int w = pos & 15, h = (pos >> 4) & 15, d = (pos >> 8) & 15, t = pos >> 12;
        int tap = ((t & 1) << 3) | ((d & 1) << 2) | ((h & 1) << 1) | (w & 1);
        int ipos = (((t >> 1) * 8 + (d >> 1)) * 8 + (h >> 1)) * 8 + (w >> 1);
        const float* xp = x1 + ((b * 64) << 12) + ipos;   // + ci*4096
        const float* wp = up_w + co * 16 + tap;           // + ci*512
        float acc = up_b[co];
        #pragma unroll 8
        for (int ci = 0; ci < 64; ++ci) {
            acc += xp[ci << 12] * wp[ci * 512];
        }
        v = acc;
    }
    xc[idx] = v;
}

// ---------------------------------------------------------------------------
// Kernel 2: 3x3x3x3 conv (pad 1), Cin=64 -> Cout=32, + bias + ReLU -> Y1 fp32.
// Block = 256 threads = (h,w) 16x16 slab; block covers (b, cog of 4 co, t, d).
// Each thread computes 4 outputs (4 co) -> each x load feeds 4 FMAs.
// ---------------------------------------------------------------------------
__global__ __launch_bounds__(256) void conv1_relu(const float* __restrict__ xc,
                                                  const float* __restrict__ w1r,
                                                  const float* __restrict__ b1,
                                                  float* __restrict__ Y1) {
    int bid = blockIdx.x;                       // [b2][cog8][t16][d16]
    int d = bid & 15, t = (bid >> 4) & 15, cog = (bid >> 8) & 7, b = bid >> 11;
    int w = threadIdx.x & 15, h = threadIdx.x >> 4;

    float4 acc;
    acc.x = b1[cog * 4 + 0];
    acc.y = b1[cog * 4 + 1];
    acc.z = b1[cog * 4 + 2];
    acc.w = b1[cog * 4 + 3];

    const float4* wr = (const float4*)w1r + cog * 81 * 64;   // [tap][ci] float4
    const float* xb = xc + ((size_t)b << 22);                // b*64*65536

    for (int ci = 0; ci < 64; ++ci) {
        const float* xci = xb + (ci << 16);
        #pragma unroll
        for (int kt = 0; kt < 3; ++kt) {
            int tt = t + kt - 1;
            if ((unsigned)tt >= 16u) continue;               // block-uniform skip
            #pragma unroll
            for (int kd = 0; kd < 3; ++kd) {
                int dd = d + kd - 1;
                if ((unsigned)dd >= 16u) continue;           // block-uniform skip
                const float* pl = xci + (tt << 12) + (dd << 8);
                #pragma unroll
                for (int kh = 0; kh < 3; ++kh) {
                    int hh = h + kh - 1;
                    bool vh = (unsigned)hh < 16u;
                    #pragma unroll
                    for (int kw = 0; kw < 3; ++kw) {
                        int ww = w + kw - 1;
                        float xv = (vh && (unsigned)ww < 16u) ? pl[(hh << 4) + ww] : 0.f;
                        float4 wv = wr[(((kt * 3 + kd) * 3 + kh) * 3 + kw) * 64 + ci];
                        acc.x += xv * wv.x;
                        acc.y += xv * wv.y;
                        acc.z += xv * wv.z;
                        acc.w += xv * wv.w;
                    }
                }
            }
        }
    }
    int pos = (((t << 4) + d) << 8) + (h << 4) + w;
    float* yb = Y1 + ((size_t)(b * 32 + cog * 4) << 16) + pos;
    yb[0 * 65536] = fmaxf(acc.x, 0.f);
    yb[1 * 65536] = fmaxf(acc.y, 0.f);
    yb[2 * 65536] = fmaxf(acc.z, 0.f);
    yb[3 * 65536] = fmaxf(acc.w, 0.f);
}

// ---------------------------------------------------------------------------
// Kernel 3: conv2 (3^4, Cin=32, pad 1) + 1x1 skip conv from xc + biases,
// final ReLU, store fp32.
// ---------------------------------------------------------------------------
__global__ __launch_bounds__(256) void conv2_sc_relu(const float* __restrict__ Y1,
                                                     const float* __restrict__ xc,
                                                     const float* __restrict__ w2r,
                                                     const float* __restrict__ w3r,
                                                     const float* __restrict__ b2,
                                                     const float* __restrict__ b3,
                                                     float* __restrict__ out) {
    int bid = blockIdx.x;
    int d = bid & 15, t = (bid >> 4) & 15, cog = (bid >> 8) & 7, b = bid >> 11;
    int w = threadIdx.x & 15, h = threadIdx.x >> 4;

    // final = relu( (conv2 + b2) + (skip + b3) ) -> start acc with b2+b3
    float4 acc;
    acc.x = b2[cog * 4 + 0] + b3[cog * 4 + 0];
    acc.y = b2[cog * 4 + 1] + b3[cog * 4 + 1];
    acc.z = b2[cog * 4 + 2] + b3[cog * 4 + 2];
    acc.w = b2[cog * 4 + 3] + b3[cog * 4 + 3];

    const float4* wr = (const float4*)w2r + cog * 81 * 32;   // [tap][ci] float4
    const float* yb = Y1 + ((size_t)(b * 32) << 16);

    for (int ci = 0; ci < 32; ++ci) {
        const float* yci = yb + (ci << 16);
        #pragma unroll
        for (int kt = 0; kt < 3; ++kt) {
            int tt = t + kt - 1;
            if ((unsigned)tt >= 16u) continue;
            #pragma unroll
            for (int kd = 0; kd < 3; ++kd) {
                int dd = d + kd - 1;
                if ((unsigned)dd >= 16u) continue;
                const float* pl = yci + (tt << 12) + (dd << 8);
                #pragma unroll
                for (int kh = 0; kh < 3; ++kh) {
                    int hh = h + kh - 1;
                    bool vh = (unsigned)hh < 16u;
                    #pragma unroll
                    for (int kw = 0; kw < 3; ++kw) {
                        int ww = w + kw - 1;
                        float xv = (vh && (unsigned)ww < 16u) ? pl[(hh << 4) + ww] : 0.f;
                        float4 wv = wr[(((kt * 3 + kd) * 3 + kh) * 3 + kw) * 32 + ci];
                        acc.x += xv * wv.x;
                        acc.y += xv * wv.y;
                        acc.z += xv * wv.z;
                        acc.w += xv * wv.w;
                    }
                }
            }
        }
    }

    // skip: 1x1x1x1 conv over xc (64 channels)
    int pos = (((t << 4) + d) << 8) + (h << 4) + w;
    const float4* w3v = (const float4*)w3r + cog * 64;
    const float* xb = xc + ((size_t)b << 22);
    for (int ci = 0; ci < 64; ++ci) {
        float xv = xb[(ci << 16) + pos];
        float4 wv = w3v[ci];
        acc.x += xv * wv.x;
        acc.y += xv * wv.y;
        acc.z += xv * wv.z;
        acc.w += xv * wv.w;
    }

    float* ob = out + ((size_t)(b * 32 + cog * 4) << 16) + pos;
    ob[0 * 65536] = fmaxf(acc.x, 0.f);
    ob[1 * 65536] = fmaxf(acc.y, 0.f);
    ob[2 * 65536] = fmaxf(acc.z, 0.f);
    ob[3 * 65536] = fmaxf(acc.w, 0.f);
}

extern "C" void kernel_launch(void* const* d_in, const int* in_sizes, int n_in,
                              void* d_out, int out_size, void* d_ws, size_t ws_size,
                              hipStream_t stream) {
    const float* x1   = (const float*)d_in[0];
    const float* x2   = (const float*)d_in[1];
    const float* up_w = (const float*)d_in[2];
    const float* up_b = (const float*)d_in[3];
    const float* w1   = (const float*)d_in[4];
    const float* b1   = (const float*)d_in[5];
    const float* w2   = (const float*)d_in[6];
    const float* b2   = (const float*)d_in[7];
    const float* w3   = (const float*)d_in[8];
    const float* b3   = (const float*)d_in[9];
    float* ws  = (float*)d_ws;
    float* out = (float*)d_out;

    // weights reorder (independent of data path)
    reorder_w<<<980, 256, 0, stream>>>(w1, w2, w3, ws);
    // upsample + concat -> xc
    up_concat<<<32768, 256, 0, stream>>>(x1, x2, up_w, up_b, ws + XC_OFF);
    // conv1 + relu -> Y1
    conv1_relu<<<4096, 256, 0, stream>>>(ws + XC_OFF, ws + W1R_OFF, b1, ws + Y1_OFF);
    // conv2 + skip + relu -> out (fp32)
    conv2_sc_relu<<<4096, 256, 0, stream>>>(ws + Y1_OFF, ws + XC_OFF, ws + W2R_OFF,
                                            ws + W3R_OFF, b2, b3, out);
}

// Round 5
// 735.603 us; speedup vs baseline: 1.9381x; 1.9381x over previous
//
#include <hip/hip_runtime.h>

typedef unsigned short u16;
typedef __attribute__((ext_vector_type(8))) short short8;   // 8 bf16 (guide-verified MFMA frag type)
typedef __attribute__((ext_vector_type(4))) float f32x4;

// Workspace layout (u16 element offsets). Total 12,833,792 u16 = 25.7 MB.
#define XCB_OFF 0          // xc  channels-last bf16 [2][16][16][16][16][64] = 8,388,608
#define Y1B_OFF 8388608    // Y1  channels-last bf16 [2][16][16][16][16][32] = 4,194,304
#define W1P_OFF 12582912   // w1 prepacked [tap81][chunk2][half2][lane64][8] = 165,888
#define W2P_OFF 12748800   // w2 prepacked [tap81][half2][lane64][8]         =  82,944
#define W3P_OFF 12831744   // w3 prepacked [chunk2][half2][lane64][8]        =   2,048

__device__ __forceinline__ u16 f2bf(float v) {   // RNE fp32 -> bf16 bits
    unsigned u = __builtin_bit_cast(unsigned, v);
    u += 0x7FFFu + ((u >> 16) & 1u);
    return (u16)(u >> 16);
}

__device__ __forceinline__ f32x4 MFMA(short8 a, short8 b, f32x4 c) {
    return __builtin_amdgcn_mfma_f32_16x16x32_bf16(a, b, c, 0, 0, 0);
}

// ---------------------------------------------------------------------------
// Prepack weights into MFMA A-fragment order (fp32 -> bf16 bits).
// A-frag (16x16x32): a[lane][j] = A[m = lane&15][k = (lane>>4)*8 + j]
// ---------------------------------------------------------------------------
__global__ void prepack_w(const float* __restrict__ w1, const float* __restrict__ w2,
                          const float* __restrict__ w3, u16* __restrict__ ws) {
    int idx = blockIdx.x * 256 + threadIdx.x;
    if (idx < 165888) {
        int j = idx & 7, lane = (idx >> 3) & 63, rest = idx >> 9;
        int half = rest & 1, chunk = (rest >> 1) & 1, tap = rest >> 2;
        int co = half * 16 + (lane & 15), ci = chunk * 32 + (lane >> 4) * 8 + j;
        ws[W1P_OFF + idx] = f2bf(w1[(co * 64 + ci) * 81 + tap]);
    } else if (idx < 165888 + 82944) {
        int i2 = idx - 165888;
        int j = i2 & 7, lane = (i2 >> 3) & 63, rest = i2 >> 9;
        int half = rest & 1, tap = rest >> 1;
        int co = half * 16 + (lane & 15), ci = (lane >> 4) * 8 + j;
        ws[W2P_OFF + i2] = f2bf(w2[(co * 32 + ci) * 81 + tap]);
    } else if (idx < 165888 + 82944 + 2048) {
        int i3 = idx - (165888 + 82944);
        int j = i3 & 7, lane = (i3 >> 3) & 63, rest = i3 >> 9;   // chunk*2+half
        int half = rest & 1, chunk = rest >> 1;
        int co = half * 16 + (lane & 15), ci = chunk * 32 + (lane >> 4) * 8 + j;
        ws[W3P_OFF + i3] = f2bf(w3[co * 64 + ci]);
    }
}

// ---------------------------------------------------------------------------
// Fused tconv4d(k2,s2) + concat -> xc channels-last bf16 bits.
// ---------------------------------------------------------------------------
__global__ void up_concat(const float* __restrict__ x1, const float* __restrict__ x2,
                          const float* __restrict__ up_w, const float* __restrict__ up_b,
                          u16* __restrict__ xcb) {
    int idx = blockIdx.x * 256 + threadIdx.x;   // (b*65536+pos)*64 + c
    int c = idx & 63;
    int pos = (idx >> 6) & 65535;
    int b = idx >> 22;
    float v;
    if (c < 32) {
        v = x2[((b * 32 + c) << 16) + pos];
    } else {
        int co = c - 32;
        int w = pos & 15, h = (pos >> 4) & 15, d = (pos >> 8) & 15, t = pos >> 12;
        int tap = ((t & 1) << 3) | ((d & 1) << 2) | ((h & 1) << 1) | (w & 1);
        int ipos = (((t >> 1) * 8 + (d >> 1)) * 8 + (h >> 1)) * 8 + (w >> 1);
        const float* xp = x1 + ((b * 64) << 12) + ipos;   // + ci*4096
        const float* wp = up_w + co * 16 + tap;           // + ci*512
        float acc = up_b[co];
        #pragma unroll 8
        for (int ci = 0; ci < 64; ++ci) acc += xp[ci << 12] * wp[ci * 512];
        v = acc;
    }
    xcb[idx] = f2bf(v);
}

// ---------------------------------------------------------------------------
// conv1: 3^4 conv, Cin=64 -> Cout=32, pad 1, +bias +ReLU -> Y1 (channels-last
// bf16). Block=128thr(2 waves): tile 8h x 16w x 32co at fixed (b,t,d).
// LDS: one (tt,dd) halo plane 10h' x 18w' x 64ci, 16B-unit XOR swizzle.
// ---------------------------------------------------------------------------
__global__ __launch_bounds__(128) void conv1_mfma(const u16* __restrict__ xcb,
                                                  const u16* __restrict__ w1p,
                                                  const float* __restrict__ b1,
                                                  u16* __restrict__ y1b) {
    __shared__ u16 lds[11520];                   // 10*18*64 = 23 KB
    int tid = threadIdx.x;
    int lane = tid & 63, wv = tid >> 6;
    int q = lane >> 4, m = lane & 15;
    int bid = blockIdx.x;                        // [b2][t16][d16][hB2]
    int hB = bid & 1, d = (bid >> 1) & 15, t = (bid >> 5) & 15, b = bid >> 9;
    int h0 = hB * 8;

    f32x4 acc[4][2];
    {
        float4 bi0 = ((const float4*)b1)[q];         // co = q*4+r      (half 0)
        float4 bi1 = ((const float4*)b1)[4 + q];     // co = 16+q*4+r   (half 1)
        #pragma unroll
        for (int i = 0; i < 4; ++i) {
            acc[i][0] = (f32x4){bi0.x, bi0.y, bi0.z, bi0.w};
            acc[i][1] = (f32x4){bi1.x, bi1.y, bi1.z, bi1.w};
        }
    }
    const short8* w1v = (const short8*)w1p;

    for (int ktd = 0; ktd < 9; ++ktd) {
        int kt = ktd / 3, kd = ktd - kt * 3;
        int tt = t + kt - 1, dd = d + kd - 1;
        bool pv = ((unsigned)tt < 16u) && ((unsigned)dd < 16u);
        __syncthreads();
        // ---- stage halo plane (zero-fill OOB) ----
        int pbase = ((b * 16 + tt) * 16 + dd) * 256;
        for (int ui = tid; ui < 1440; ui += 128) {   // 10*18*8 16B-units
            int u = ui & 7, p = (ui >> 3) % 18, hh = ui / 144;
            int gh = h0 - 1 + hh, gw = p - 1;
            uint4 val = {0, 0, 0, 0};
            if (pv && (unsigned)gh < 16u && (unsigned)gw < 16u) {
                val = *(const uint4*)(xcb + (size_t)(pbase + gh * 16 + gw) * 64 + u * 8);
            }
            *(uint4*)(lds + hh * 1152 + p * 64 + ((u ^ (p & 7)) * 8)) = val;
        }
        __syncthreads();
        // ---- MFMA over (kh,kw) x ci-chunks ----
        #pragma unroll
        for (int kh = 0; kh < 3; ++kh) {
            #pragma unroll
            for (int kw = 0; kw < 3; ++kw) {
                int tap = (ktd * 3 + kh) * 3 + kw;
                int p = kw + m, pm = p & 7;
                #pragma unroll
                for (int chunk = 0; chunk < 2; ++chunk) {
                    short8 a0 = w1v[((tap * 2 + chunk) * 2 + 0) * 64 + lane];
                    short8 a1 = w1v[((tap * 2 + chunk) * 2 + 1) * 64 + lane];
                    int bo = p * 64 + ((((chunk << 2) | q) ^ pm) << 3);
                    #pragma unroll
                    for (int i = 0; i < 4; ++i) {
                        short8 bf = *(const short8*)(lds + (wv * 4 + i + kh) * 1152 + bo);
                        acc[i][0] = MFMA(a0, bf, acc[i][0]);
                        acc[i][1] = MFMA(a1, bf, acc[i][1]);
                    }
                }
            }
        }
    }
    // ---- epilogue: ReLU, store channels-last bf16 bits ----
    // C/D: col(pos) = lane&15, row(co within half) = q*4 + r
    // y1b is [global_pos][ci] -> keep b folded into pos here (in-bounds: pos<131072).
    int obase = ((b * 16 + t) * 16 + d) * 256 + (h0 + wv * 4) * 16 + m;
    #pragma unroll
    for (int i = 0; i < 4; ++i) {
        int pos = obase + i * 16;
        #pragma unroll
        for (int half = 0; half < 2; ++half) {
            f32x4 v = acc[i][half];
            unsigned r0 = f2bf(fmaxf(v.x, 0.f)), r1 = f2bf(fmaxf(v.y, 0.f));
            unsigned r2 = f2bf(fmaxf(v.z, 0.f)), r3 = f2bf(fmaxf(v.w, 0.f));
            uint2 o;
            o.x = r0 | (r1 << 16);
            o.y = r2 | (r3 << 16);
            *(uint2*)(y1b + (size_t)pos * 32 + half * 16 + q * 4) = o;
        }
    }
}

// ---------------------------------------------------------------------------
// conv2: 3^4 conv Cin=32->Cout=32 on Y1 + fused 1x1 skip (xc, Cin=64) + biases
// + final ReLU -> fp32 output in reference layout [b][co][t][d][h][w].
// ---------------------------------------------------------------------------
__global__ __launch_bounds__(128) void conv2_mfma(const u16* __restrict__ y1b,
                                                  const u16* __restrict__ xcb,
                                                  const u16* __restrict__ w2p,
                                                  const u16* __restrict__ w3p,
                                                  const float* __restrict__ b2,
                                                  const float* __restrict__ b3,
                                                  float* __restrict__ out) {
    __shared__ u16 lds[5760];                    // 10*18*32 = 11.5 KB
    int tid = threadIdx.x;
    int lane = tid & 63, wv = tid >> 6;
    int q = lane >> 4, m = lane & 15;
    int bid = blockIdx.x;
    int hB = bid & 1, d = (bid >> 1) & 15, t = (bid >> 5) & 15, b = bid >> 9;
    int h0 = hB * 8;

    f32x4 acc[4][2];
    {
        float4 p0 = ((const float4*)b2)[q];
        float4 p1 = ((const float4*)b2)[4 + q];
        float4 s0 = ((const float4*)b3)[q];
        float4 s1 = ((const float4*)b3)[4 + q];
        #pragma unroll
        for (int i = 0; i < 4; ++i) {
            acc[i][0] = (f32x4){p0.x + s0.x, p0.y + s0.y, p0.z + s0.z, p0.w + s0.w};
            acc[i][1] = (f32x4){p1.x + s1.x, p1.y + s1.y, p1.z + s1.z, p1.w + s1.w};
        }
    }
    const short8* w2v = (const short8*)w2p;

    for (int ktd = 0; ktd < 9; ++ktd) {
        int kt = ktd / 3, kd = ktd - kt * 3;
        int tt = t + kt - 1, dd = d + kd - 1;
        bool pv = ((unsigned)tt < 16u) && ((unsigned)dd < 16u);
        __syncthreads();
        int pbase = ((b * 16 + tt) * 16 + dd) * 256;
        for (int ui = tid; ui < 720; ui += 128) {    // 10*18*4 16B-units
            int u = ui & 3, p = (ui >> 2) % 18, hh = ui / 72;
            int gh = h0 - 1 + hh, gw = p - 1;
            uint4 val = {0, 0, 0, 0};
            if (pv && (unsigned)gh < 16u && (unsigned)gw < 16u) {
                val = *(const uint4*)(y1b + (size_t)(pbase + gh * 16 + gw) * 32 + u * 8);
            }
            *(uint4*)(lds + hh * 576 + p * 32 + ((u ^ (p & 3)) * 8)) = val;
        }
        __syncthreads();
        #pragma unroll
        for (int kh = 0; kh < 3; ++kh) {
            #pragma unroll
            for (int kw = 0; kw < 3; ++kw) {
                int tap = (ktd * 3 + kh) * 3 + kw;
                int p = kw + m, pm = p & 3;
                short8 a0 = w2v[(tap * 2 + 0) * 64 + lane];
                short8 a1 = w2v[(tap * 2 + 1) * 64 + lane];
                int bo = p * 32 + ((q ^ pm) << 3);
                #pragma unroll
                for (int i = 0; i < 4; ++i) {
                    short8 bf = *(const short8*)(lds + (wv * 4 + i + kh) * 576 + bo);
                    acc[i][0] = MFMA(a0, bf, acc[i][0]);
                    acc[i][1] = MFMA(a1, bf, acc[i][1]);
                }
            }
        }
    }

    // ---- fused 1x1 skip conv from xc (Cin=64, 2 chunks), B direct from global
    const short8* w3v = (const short8*)w3p;
    int lpos0 = ((t * 16 + d) * 256) + (h0 + wv * 4) * 16 + m;   // batch-local pos
    int gpos0 = (b << 16) + lpos0;                               // global pos (ws arrays)
    #pragma unroll
    for (int chunk = 0; chunk < 2; ++chunk) {
        short8 a0 = w3v[(chunk * 2 + 0) * 64 + lane];
        short8 a1 = w3v[(chunk * 2 + 1) * 64 + lane];
        #pragma unroll
        for (int i = 0; i < 4; ++i) {
            short8 bf = *(const short8*)(xcb + (size_t)(gpos0 + i * 16) * 64 + ((chunk << 2) | q) * 8);
            acc[i][0] = MFMA(a0, bf, acc[i][0]);
            acc[i][1] = MFMA(a1, bf, acc[i][1]);
        }
    }

    // ---- epilogue: ReLU, fp32 store to [b][co][local_pos] ----
    // BUGFIX (r3/r4 abort): out index must use batch-LOCAL pos; using the
    // b-folded pos wrote up to 256 KB past d_out for b=1 -> GPU fault.
    #pragma unroll
    for (int i = 0; i < 4; ++i) {
        int lpos = lpos0 + i * 16;
        #pragma unroll
        for (int half = 0; half < 2; ++half) {
            f32x4 v = acc[i][half];
            int co = half * 16 + q * 4;
            float* op = out + (((size_t)(b * 32 + co)) << 16) + lpos;
            op[0ull << 16] = fmaxf(v.x, 0.f);
            op[1ull << 16] = fmaxf(v.y, 0.f);
            op[2ull << 16] = fmaxf(v.z, 0.f);
            op[3ull << 16] = fmaxf(v.w, 0.f);
        }
    }
}

extern "C" void kernel_launch(void* const* d_in, const int* in_sizes, int n_in,
                              void* d_out, int out_size, void* d_ws, size_t ws_size,
                              hipStream_t stream) {
    const float* x1   = (const float*)d_in[0];
    const float* x2   = (const float*)d_in[1];
    const float* up_w = (const float*)d_in[2];
    const float* up_b = (const float*)d_in[3];
    const float* w1   = (const float*)d_in[4];
    const float* b1   = (const float*)d_in[5];
    const float* w2   = (const float*)d_in[6];
    const float* b2   = (const float*)d_in[7];
    const float* w3   = (const float*)d_in[8];
    const float* b3   = (const float*)d_in[9];
    u16* ws  = (u16*)d_ws;
    float* out = (float*)d_out;

    prepack_w<<<980, 256, 0, stream>>>(w1, w2, w3, ws);
    up_concat<<<32768, 256, 0, stream>>>(x1, x2, up_w, up_b, ws + XCB_OFF);
    conv1_mfma<<<1024, 128, 0, stream>>>(ws + XCB_OFF, ws + W1P_OFF, b1, ws + Y1B_OFF);
    conv2_mfma<<<1024, 128, 0, stream>>>(ws + Y1B_OFF, ws + XCB_OFF, ws + W2P_OFF,
                                         ws + W3P_OFF, b2, b3, out);
}

// Round 6
// 269.575 us; speedup vs baseline: 5.2887x; 2.7288x over previous
//
#include <hip/hip_runtime.h>

typedef unsigned short u16;
typedef __attribute__((ext_vector_type(8))) short short8;   // 8 bf16 (guide-verified MFMA frag type)
typedef __attribute__((ext_vector_type(4))) float f32x4;

// Workspace layout (u16 element offsets). Total 12,899,328 u16 = 25.8 MB.
#define XCB_OFF 0          // xc  channels-last bf16 [2][16][16][16][16][64] = 8,388,608
#define Y1B_OFF 8388608    // Y1  channels-last bf16 [2][16][16][16][16][32] = 4,194,304
#define W1P_OFF 12582912   // w1 prepacked [tap81][chunk2][half2][lane64][8] = 165,888
#define W2P_OFF 12748800   // w2 prepacked [tap81][half2][lane64][8]         =  82,944
#define W3P_OFF 12831744   // w3 prepacked [chunk2][half2][lane64][8]        =   2,048
#define UPW_OFF 12833792   // up_w prepacked fp32 [tap16][ci64][co32]        = 32,768 fp32 = 65,536 u16

__device__ __forceinline__ u16 f2bf(float v) {   // RNE fp32 -> bf16 bits
    unsigned u = __builtin_bit_cast(unsigned, v);
    u += 0x7FFFu + ((u >> 16) & 1u);
    return (u16)(u >> 16);
}

__device__ __forceinline__ f32x4 MFMA(short8 a, short8 b, f32x4 c) {
    return __builtin_amdgcn_mfma_f32_16x16x32_bf16(a, b, c, 0, 0, 0);
}

// ---------------------------------------------------------------------------
// Prepack weights. w1/w2/w3 into MFMA A-fragment order (bf16 bits);
// up_w into [tap][ci][co] fp32 (lane-contiguous co for the upsample kernel).
// ---------------------------------------------------------------------------
__global__ void prepack_w(const float* __restrict__ w1, const float* __restrict__ w2,
                          const float* __restrict__ w3, const float* __restrict__ upw,
                          u16* __restrict__ ws) {
    int idx = blockIdx.x * 256 + threadIdx.x;
    if (idx < 165888) {
        int j = idx & 7, lane = (idx >> 3) & 63, rest = idx >> 9;
        int half = rest & 1, chunk = (rest >> 1) & 1, tap = rest >> 2;
        int co = half * 16 + (lane & 15), ci = chunk * 32 + (lane >> 4) * 8 + j;
        ws[W1P_OFF + idx] = f2bf(w1[(co * 64 + ci) * 81 + tap]);
    } else if (idx < 165888 + 82944) {
        int i2 = idx - 165888;
        int j = i2 & 7, lane = (i2 >> 3) & 63, rest = i2 >> 9;
        int half = rest & 1, tap = rest >> 1;
        int co = half * 16 + (lane & 15), ci = (lane >> 4) * 8 + j;
        ws[W2P_OFF + i2] = f2bf(w2[(co * 32 + ci) * 81 + tap]);
    } else if (idx < 165888 + 82944 + 2048) {
        int i3 = idx - (165888 + 82944);
        int j = i3 & 7, lane = (i3 >> 3) & 63, rest = i3 >> 9;   // chunk*2+half
        int half = rest & 1, chunk = rest >> 1;
        int co = half * 16 + (lane & 15), ci = chunk * 32 + (lane >> 4) * 8 + j;
        ws[W3P_OFF + i3] = f2bf(w3[co * 64 + ci]);
    } else if (idx < 165888 + 82944 + 2048 + 32768) {
        int i4 = idx - (165888 + 82944 + 2048);        // (tap*64+ci)*32+co
        int co = i4 & 31, ci = (i4 >> 5) & 63, tap = i4 >> 11;
        ((float*)(ws + UPW_OFF))[i4] = upw[(ci * 32 + co) * 16 + tap];
    }
}

// ---------------------------------------------------------------------------
// xc_copy: x2 (channel-major fp32) -> xcb channels 0..31 (channels-last bf16)
// via padded-LDS tile transpose. Block = 256 thr, tile = 256 pos x 32 c.
// ---------------------------------------------------------------------------
__global__ __launch_bounds__(256) void xc_copy(const float* __restrict__ x2,
                                               u16* __restrict__ xcb) {
    __shared__ u16 lds[256 * 34];                // pad 34: conflict-free transpose
    int tid = threadIdx.x;
    int b = blockIdx.x >> 8;
    int pos_base = (blockIdx.x & 255) * 256;
    #pragma unroll
    for (int c = 0; c < 32; ++c) {               // coalesced 1KB reads per c-row
        lds[tid * 34 + c] = f2bf(x2[((b * 32 + c) << 16) + pos_base + tid]);
    }
    __syncthreads();
    #pragma unroll
    for (int k = 0; k < 32; ++k) {               // c-major stores: 2x64B lines/wave
        int f = k * 256 + tid;
        int c = f & 31, pos = f >> 5;
        xcb[(size_t)((b << 16) + pos_base + pos) * 64 + c] = lds[pos * 34 + c];
    }
}

// ---------------------------------------------------------------------------
// xc_up: tconv4d(k2,s2) -> xcb channels 32..63. One wave = 2 output pos
// (same tap, w and w+2) x 32 co. Weight loads contiguous (co-lane), x1 loads
// broadcast -> ~128 cache lines/wave vs ~2100 in the old divergent kernel.
// ---------------------------------------------------------------------------
__global__ __launch_bounds__(256) void xc_up(const float* __restrict__ x1,
                                             const float* __restrict__ upw_f32,
                                             const float* __restrict__ up_b,
                                             u16* __restrict__ xcb) {
    int tid = threadIdx.x;
    int wid = blockIdx.x * 4 + (tid >> 6);       // 65536 waves
    int l = tid & 63;
    int co = l & 31, wpair = l >> 5;
    int wp = wid & 7, h = (wid >> 3) & 15, d = (wid >> 7) & 15,
        t = (wid >> 11) & 15, b = wid >> 15;
    int w0 = (wp >> 1) * 4 + (wp & 1);           // {0,1,4,5,8,9,12,13}
    int w = w0 + 2 * wpair;
    int tap = ((t & 1) << 3) | ((d & 1) << 2) | ((h & 1) << 1) | (w0 & 1);
    int ibase = (((t >> 1) * 8 + (d >> 1)) * 8 + (h >> 1)) * 8 + (w0 >> 1) + wpair;
    const float* xp = x1 + (size_t)(b * 64) * 4096 + ibase;   // + ci*4096
    const float* wpk = upw_f32 + (tap * 64) * 32 + co;        // + ci*32
    float acc = 0.f;
    #pragma unroll 4
    for (int ci = 0; ci < 64; ++ci) {
        acc += xp[ci * 4096] * wpk[ci * 32];
    }
    acc += up_b[co];
    int gpos = (b << 16) + t * 4096 + d * 256 + h * 16 + w;
    xcb[(size_t)gpos * 64 + 32 + co] = f2bf(acc);
}

// ---------------------------------------------------------------------------
// conv1: 3^4 conv, Cin=64 -> Cout=32, pad 1, +bias +ReLU -> Y1 (channels-last
// bf16). Block=128thr(2 waves): tile 8h x 16w x 32co at fixed (b,t,d).
// LDS: one (tt,dd) halo plane 10h' x 18w' x 64ci, 16B-unit XOR swizzle.
// ---------------------------------------------------------------------------
__global__ __launch_bounds__(128) void conv1_mfma(const u16* __restrict__ xcb,
                                                  const u16* __restrict__ w1p,
                                                  const float* __restrict__ b1,
                                                  u16* __restrict__ y1b) {
    __shared__ u16 lds[11520];                   // 10*18*64 = 23 KB
    int tid = threadIdx.x;
    int lane = tid & 63, wv = tid >> 6;
    int q = lane >> 4, m = lane & 15;
    int bid = blockIdx.x;                        // [b2][t16][d16][hB2]
    int hB = bid & 1, d = (bid >> 1) & 15, t = (bid >> 5) & 15, b = bid >> 9;
    int h0 = hB * 8;

    f32x4 acc[4][2];
    {
        float4 bi0 = ((const float4*)b1)[q];         // co = q*4+r      (half 0)
        float4 bi1 = ((const float4*)b1)[4 + q];     // co = 16+q*4+r   (half 1)
        #pragma unroll
        for (int i = 0; i < 4; ++i) {
            acc[i][0] = (f32x4){bi0.x, bi0.y, bi0.z, bi0.w};
            acc[i][1] = (f32x4){bi1.x, bi1.y, bi1.z, bi1.w};
        }
    }
    const short8* w1v = (const short8*)w1p;

    for (int ktd = 0; ktd < 9; ++ktd) {
        int kt = ktd / 3, kd = ktd - kt * 3;
        int tt = t + kt - 1, dd = d + kd - 1;
        bool pv = ((unsigned)tt < 16u) && ((unsigned)dd < 16u);
        __syncthreads();
        // ---- stage halo plane (zero-fill OOB) ----
        int pbase = ((b * 16 + tt) * 16 + dd) * 256;
        for (int ui = tid; ui < 1440; ui += 128) {   // 10*18*8 16B-units
            int u = ui & 7, p = (ui >> 3) % 18, hh = ui / 144;
            int gh = h0 - 1 + hh, gw = p - 1;
            uint4 val = {0, 0, 0, 0};
            if (pv && (unsigned)gh < 16u && (unsigned)gw < 16u) {
                val = *(const uint4*)(xcb + (size_t)(pbase + gh * 16 + gw) * 64 + u * 8);
            }
            *(uint4*)(lds + hh * 1152 + p * 64 + ((u ^ (p & 7)) * 8)) = val;
        }
        __syncthreads();
        // ---- MFMA over (kh,kw) x ci-chunks ----
        #pragma unroll
        for (int kh = 0; kh < 3; ++kh) {
            #pragma unroll
            for (int kw = 0; kw < 3; ++kw) {
                int tap = (ktd * 3 + kh) * 3 + kw;
                int p = kw + m, pm = p & 7;
                #pragma unroll
                for (int chunk = 0; chunk < 2; ++chunk) {
                    short8 a0 = w1v[((tap * 2 + chunk) * 2 + 0) * 64 + lane];
                    short8 a1 = w1v[((tap * 2 + chunk) * 2 + 1) * 64 + lane];
                    int bo = p * 64 + ((((chunk << 2) | q) ^ pm) << 3);
                    #pragma unroll
                    for (int i = 0; i < 4; ++i) {
                        short8 bf = *(const short8*)(lds + (wv * 4 + i + kh) * 1152 + bo);
                        acc[i][0] = MFMA(a0, bf, acc[i][0]);
                        acc[i][1] = MFMA(a1, bf, acc[i][1]);
                    }
                }
            }
        }
    }
    // ---- epilogue: ReLU, store channels-last bf16 bits ----
    int obase = ((b * 16 + t) * 16 + d) * 256 + (h0 + wv * 4) * 16 + m;
    #pragma unroll
    for (int i = 0; i < 4; ++i) {
        int pos = obase + i * 16;
        #pragma unroll
        for (int half = 0; half < 2; ++half) {
            f32x4 v = acc[i][half];
            unsigned r0 = f2bf(fmaxf(v.x, 0.f)), r1 = f2bf(fmaxf(v.y, 0.f));
            unsigned r2 = f2bf(fmaxf(v.z, 0.f)), r3 = f2bf(fmaxf(v.w, 0.f));
            uint2 o;
            o.x = r0 | (r1 << 16);
            o.y = r2 | (r3 << 16);
            *(uint2*)(y1b + (size_t)pos * 32 + half * 16 + q * 4) = o;
        }
    }
}

// ---------------------------------------------------------------------------
// conv2: 3^4 conv Cin=32->Cout=32 on Y1 + fused 1x1 skip (xc, Cin=64) + biases
// + final ReLU -> fp32 output in reference layout [b][co][t][d][h][w].
// ---------------------------------------------------------------------------
__global__ __launch_bounds__(128) void conv2_mfma(const u16* __restrict__ y1b,
                                                  const u16* __restrict__ xcb,
                                                  const u16* __restrict__ w2p,
                                                  const u16* __restrict__ w3p,
                                                  const float* __restrict__ b2,
                                                  const float* __restrict__ b3,
                                                  float* __restrict__ out) {
    __shared__ u16 lds[5760];                    // 10*18*32 = 11.5 KB
    int tid = threadIdx.x;
    int lane = tid & 63, wv = tid >> 6;
    int q = lane >> 4, m = lane & 15;
    int bid = blockIdx.x;
    int hB = bid & 1, d = (bid >> 1) & 15, t = (bid >> 5) & 15, b = bid >> 9;
    int h0 = hB * 8;

    f32x4 acc[4][2];
    {
        float4 p0 = ((const float4*)b2)[q];
        float4 p1 = ((const float4*)b2)[4 + q];
        float4 s0 = ((const float4*)b3)[q];
        float4 s1 = ((const float4*)b3)[4 + q];
        #pragma unroll
        for (int i = 0; i < 4; ++i) {
            acc[i][0] = (f32x4){p0.x + s0.x, p0.y + s0.y, p0.z + s0.z, p0.w + s0.w};
            acc[i][1] = (f32x4){p1.x + s1.x, p1.y + s1.y, p1.z + s1.z, p1.w + s1.w};
        }
    }
    const short8* w2v = (const short8*)w2p;

    for (int ktd = 0; ktd < 9; ++ktd) {
        int kt = ktd / 3, kd = ktd - kt * 3;
        int tt = t + kt - 1, dd = d + kd - 1;
        bool pv = ((unsigned)tt < 16u) && ((unsigned)dd < 16u);
        __syncthreads();
        int pbase = ((b * 16 + tt) * 16 + dd) * 256;
        for (int ui = tid; ui < 720; ui += 128) {    // 10*18*4 16B-units
            int u = ui & 3, p = (ui >> 2) % 18, hh = ui / 72;
            int gh = h0 - 1 + hh, gw = p - 1;
            uint4 val = {0, 0, 0, 0};
            if (pv && (unsigned)gh < 16u && (unsigned)gw < 16u) {
                val = *(const uint4*)(y1b + (size_t)(pbase + gh * 16 + gw) * 32 + u * 8);
            }
            *(uint4*)(lds + hh * 576 + p * 32 + ((u ^ (p & 3)) * 8)) = val;
        }
        __syncthreads();
        #pragma unroll
        for (int kh = 0; kh < 3; ++kh) {
            #pragma unroll
            for (int kw = 0; kw < 3; ++kw) {
                int tap = (ktd * 3 + kh) * 3 + kw;
                int p = kw + m, pm = p & 3;
                short8 a0 = w2v[(tap * 2 + 0) * 64 + lane];
                short8 a1 = w2v[(tap * 2 + 1) * 64 + lane];
                int bo = p * 32 + ((q ^ pm) << 3);
                #pragma unroll
                for (int i = 0; i < 4; ++i) {
                    short8 bf = *(const short8*)(lds + (wv * 4 + i + kh) * 576 + bo);
                    acc[i][0] = MFMA(a0, bf, acc[i][0]);
                    acc[i][1] = MFMA(a1, bf, acc[i][1]);
                }
            }
        }
    }

    // ---- fused 1x1 skip conv from xc (Cin=64, 2 chunks), B direct from global
    const short8* w3v = (const short8*)w3p;
    int lpos0 = ((t * 16 + d) * 256) + (h0 + wv * 4) * 16 + m;   // batch-local pos
    int gpos0 = (b << 16) + lpos0;                               // global pos (ws arrays)
    #pragma unroll
    for (int chunk = 0; chunk < 2; ++chunk) {
        short8 a0 = w3v[(chunk * 2 + 0) * 64 + lane];
        short8 a1 = w3v[(chunk * 2 + 1) * 64 + lane];
        #pragma unroll
        for (int i = 0; i < 4; ++i) {
            short8 bf = *(const short8*)(xcb + (size_t)(gpos0 + i * 16) * 64 + ((chunk << 2) | q) * 8);
            acc[i][0] = MFMA(a0, bf, acc[i][0]);
            acc[i][1] = MFMA(a1, bf, acc[i][1]);
        }
    }

    // ---- epilogue: ReLU, fp32 store to [b][co][local_pos] ----
    #pragma unroll
    for (int i = 0; i < 4; ++i) {
        int lpos = lpos0 + i * 16;
        #pragma unroll
        for (int half = 0; half < 2; ++half) {
            f32x4 v = acc[i][half];
            int co = half * 16 + q * 4;
            float* op = out + (((size_t)(b * 32 + co)) << 16) + lpos;
            op[0ull << 16] = fmaxf(v.x, 0.f);
            op[1ull << 16] = fmaxf(v.y, 0.f);
            op[2ull << 16] = fmaxf(v.z, 0.f);
            op[3ull << 16] = fmaxf(v.w, 0.f);
        }
    }
}

extern "C" void kernel_launch(void* const* d_in, const int* in_sizes, int n_in,
                              void* d_out, int out_size, void* d_ws, size_t ws_size,
                              hipStream_t stream) {
    const float* x1   = (const float*)d_in[0];
    const float* x2   = (const float*)d_in[1];
    const float* up_w = (const float*)d_in[2];
    const float* up_b = (const float*)d_in[3];
    const float* w1   = (const float*)d_in[4];
    const float* b1   = (const float*)d_in[5];
    const float* w2   = (const float*)d_in[6];
    const float* b2   = (const float*)d_in[7];
    const float* w3   = (const float*)d_in[8];
    const float* b3   = (const float*)d_in[9];
    u16* ws  = (u16*)d_ws;
    float* out = (float*)d_out;

    prepack_w<<<1108, 256, 0, stream>>>(w1, w2, w3, up_w, ws);
    xc_copy<<<512, 256, 0, stream>>>(x2, ws + XCB_OFF);
    xc_up<<<16384, 256, 0, stream>>>(x1, (const float*)(ws + UPW_OFF), up_b, ws + XCB_OFF);
    conv1_mfma<<<1024, 128, 0, stream>>>(ws + XCB_OFF, ws + W1P_OFF, b1, ws + Y1B_OFF);
    conv2_mfma<<<1024, 128, 0, stream>>>(ws + Y1B_OFF, ws + XCB_OFF, ws + W2P_OFF,
                                         ws + W3P_OFF, b2, b3, out);
}

// Round 7
// 249.109 us; speedup vs baseline: 5.7232x; 1.0822x over previous
//
#include <hip/hip_runtime.h>

typedef unsigned short u16;
typedef __attribute__((ext_vector_type(8))) short short8;   // 8 bf16 (guide-verified MFMA frag type)
typedef __attribute__((ext_vector_type(4))) float f32x4;

// Workspace layout (u16 element offsets). Total 12,899,328 u16 = 25.8 MB.
#define XCB_OFF 0          // xc  channels-last bf16 [2][16][16][16][16][64] = 8,388,608
#define Y1B_OFF 8388608    // Y1  channels-last bf16 [2][16][16][16][16][32] = 4,194,304
#define W1P_OFF 12582912   // w1 prepacked [tap81][chunk2][half2][lane64][8] = 165,888
#define W2P_OFF 12748800   // w2 prepacked [tap81][half2][lane64][8]         =  82,944
#define W3P_OFF 12831744   // w3 prepacked [chunk2][half2][lane64][8]        =   2,048
#define UPW_OFF 12833792   // up_w prepacked fp32 [tap16][ci64][co32]        = 32,768 fp32 = 65,536 u16

__device__ __forceinline__ u16 f2bf(float v) {   // RNE fp32 -> bf16 bits
    unsigned u = __builtin_bit_cast(unsigned, v);
    u += 0x7FFFu + ((u >> 16) & 1u);
    return (u16)(u >> 16);
}

__device__ __forceinline__ f32x4 MFMA(short8 a, short8 b, f32x4 c) {
    return __builtin_amdgcn_mfma_f32_16x16x32_bf16(a, b, c, 0, 0, 0);
}

// bid decode shared by conv kernels: grid 2048 = [b2][t16][d16][hB4],
// arranged so xcd = bid&7 pins each XCD to a t-pair (L2 locality).
__device__ __forceinline__ void decode_bid(int bid, int& b, int& t, int& d, int& h0) {
    int xcd = bid & 7, loc = bid >> 3;
    int hB = loc & 3;
    d = (loc >> 2) & 15;
    int tsub = (loc >> 6) & 1;
    b = loc >> 7;
    t = xcd * 2 + tsub;
    h0 = hB * 4;
}

// ---------------------------------------------------------------------------
// Prepack weights. w1/w2/w3 into MFMA A-fragment order (bf16 bits);
// up_w into [tap][ci][co] fp32 (lane-contiguous co for the upsample kernel).
// ---------------------------------------------------------------------------
__global__ void prepack_w(const float* __restrict__ w1, const float* __restrict__ w2,
                          const float* __restrict__ w3, const float* __restrict__ upw,
                          u16* __restrict__ ws) {
    int idx = blockIdx.x * 256 + threadIdx.x;
    if (idx < 165888) {
        int j = idx & 7, lane = (idx >> 3) & 63, rest = idx >> 9;
        int half = rest & 1, chunk = (rest >> 1) & 1, tap = rest >> 2;
        int co = half * 16 + (lane & 15), ci = chunk * 32 + (lane >> 4) * 8 + j;
        ws[W1P_OFF + idx] = f2bf(w1[(co * 64 + ci) * 81 + tap]);
    } else if (idx < 165888 + 82944) {
        int i2 = idx - 165888;
        int j = i2 & 7, lane = (i2 >> 3) & 63, rest = i2 >> 9;
        int half = rest & 1, tap = rest >> 1;
        int co = half * 16 + (lane & 15), ci = (lane >> 4) * 8 + j;
        ws[W2P_OFF + i2] = f2bf(w2[(co * 32 + ci) * 81 + tap]);
    } else if (idx < 165888 + 82944 + 2048) {
        int i3 = idx - (165888 + 82944);
        int j = i3 & 7, lane = (i3 >> 3) & 63, rest = i3 >> 9;   // chunk*2+half
        int half = rest & 1, chunk = rest >> 1;
        int co = half * 16 + (lane & 15), ci = chunk * 32 + (lane >> 4) * 8 + j;
        ws[W3P_OFF + i3] = f2bf(w3[co * 64 + ci]);
    } else if (idx < 165888 + 82944 + 2048 + 32768) {
        int i4 = idx - (165888 + 82944 + 2048);        // (tap*64+ci)*32+co
        int co = i4 & 31, ci = (i4 >> 5) & 63, tap = i4 >> 11;
        ((float*)(ws + UPW_OFF))[i4] = upw[(ci * 32 + co) * 16 + tap];
    }
}

// ---------------------------------------------------------------------------
// xc_copy: x2 (channel-major fp32) -> xcb channels 0..31 (channels-last bf16)
// via padded-LDS tile transpose. Block = 256 thr, tile = 256 pos x 32 c.
// ---------------------------------------------------------------------------
__global__ __launch_bounds__(256) void xc_copy(const float* __restrict__ x2,
                                               u16* __restrict__ xcb) {
    __shared__ u16 lds[256 * 34];                // pad 34: conflict-free transpose
    int tid = threadIdx.x;
    int b = blockIdx.x >> 8;
    int pos_base = (blockIdx.x & 255) * 256;
    #pragma unroll
    for (int c = 0; c < 32; ++c) {               // coalesced 1KB reads per c-row
        lds[tid * 34 + c] = f2bf(x2[((b * 32 + c) << 16) + pos_base + tid]);
    }
    __syncthreads();
    #pragma unroll
    for (int k = 0; k < 32; ++k) {               // c-major stores: 2x64B lines/wave
        int f = k * 256 + tid;
        int c = f & 31, pos = f >> 5;
        xcb[(size_t)((b << 16) + pos_base + pos) * 64 + c] = lds[pos * 34 + c];
    }
}

// ---------------------------------------------------------------------------
// xc_up: tconv4d(k2,s2) -> xcb channels 32..63. One wave = 2 output pos
// (same tap, w and w+2) x 32 co. Weight loads contiguous (co-lane), x1 loads
// broadcast.
// ---------------------------------------------------------------------------
__global__ __launch_bounds__(256) void xc_up(const float* __restrict__ x1,
                                             const float* __restrict__ upw_f32,
                                             const float* __restrict__ up_b,
                                             u16* __restrict__ xcb) {
    int tid = threadIdx.x;
    int wid = blockIdx.x * 4 + (tid >> 6);       // 65536 waves
    int l = tid & 63;
    int co = l & 31, wpair = l >> 5;
    int wp = wid & 7, h = (wid >> 3) & 15, d = (wid >> 7) & 15,
        t = (wid >> 11) & 15, b = wid >> 15;
    int w0 = (wp >> 1) * 4 + (wp & 1);           // {0,1,4,5,8,9,12,13}
    int w = w0 + 2 * wpair;
    int tap = ((t & 1) << 3) | ((d & 1) << 2) | ((h & 1) << 1) | (w0 & 1);
    int ibase = (((t >> 1) * 8 + (d >> 1)) * 8 + (h >> 1)) * 8 + (w0 >> 1) + wpair;
    const float* xp = x1 + (size_t)(b * 64) * 4096 + ibase;   // + ci*4096
    const float* wpk = upw_f32 + (tap * 64) * 32 + co;        // + ci*32
    float acc = 0.f;
    #pragma unroll 4
    for (int ci = 0; ci < 64; ++ci) {
        acc += xp[ci * 4096] * wpk[ci * 32];
    }
    acc += up_b[co];
    int gpos = (b << 16) + t * 4096 + d * 256 + h * 16 + w;
    xcb[(size_t)gpos * 64 + 32 + co] = f2bf(acc);
}

// ---------------------------------------------------------------------------
// conv1: 3^4 conv, Cin=64 -> Cout=32, pad 1, +bias +ReLU -> Y1 (channels-last
// bf16). Block=128thr(2 waves): tile 4h x 16w x 32co at fixed (b,t,d).
// Grid 2048 -> 8 blocks/CU residency (was 1024/4: occupancy-limited).
// LDS: one (tt,dd) halo plane 6h' x 18w' x 64ci, 16B-unit XOR swizzle.
// ---------------------------------------------------------------------------
__global__ __launch_bounds__(128) void conv1_mfma(const u16* __restrict__ xcb,
                                                  const u16* __restrict__ w1p,
                                                  const float* __restrict__ b1,
                                                  u16* __restrict__ y1b) {
    __shared__ u16 lds[6912];                    // 6*18*64 = 13.8 KB
    int tid = threadIdx.x;
    int lane = tid & 63, wv = tid >> 6;
    int q = lane >> 4, m = lane & 15;
    int b, t, d, h0;
    decode_bid(blockIdx.x, b, t, d, h0);

    f32x4 acc[2][2];
    {
        float4 bi0 = ((const float4*)b1)[q];         // co = q*4+r      (half 0)
        float4 bi1 = ((const float4*)b1)[4 + q];     // co = 16+q*4+r   (half 1)
        #pragma unroll
        for (int i = 0; i < 2; ++i) {
            acc[i][0] = (f32x4){bi0.x, bi0.y, bi0.z, bi0.w};
            acc[i][1] = (f32x4){bi1.x, bi1.y, bi1.z, bi1.w};
        }
    }
    const short8* w1v = (const short8*)w1p;

    for (int ktd = 0; ktd < 9; ++ktd) {
        int kt = ktd / 3, kd = ktd - kt * 3;
        int tt = t + kt - 1, dd = d + kd - 1;
        bool pv = ((unsigned)tt < 16u) && ((unsigned)dd < 16u);
        __syncthreads();
        // ---- stage halo plane (zero-fill OOB) ----
        int pbase = ((b * 16 + tt) * 16 + dd) * 256;
        for (int ui = tid; ui < 864; ui += 128) {    // 6*18*8 16B-units
            int u = ui & 7, p = (ui >> 3) % 18, hh = ui / 144;
            int gh = h0 - 1 + hh, gw = p - 1;
            uint4 val = {0, 0, 0, 0};
            if (pv && (unsigned)gh < 16u && (unsigned)gw < 16u) {
                val = *(const uint4*)(xcb + (size_t)(pbase + gh * 16 + gw) * 64 + u * 8);
            }
            *(uint4*)(lds + hh * 1152 + p * 64 + ((u ^ (p & 7)) * 8)) = val;
        }
        __syncthreads();
        // ---- MFMA over (kh,kw) x ci-chunks ----
        #pragma unroll
        for (int kh = 0; kh < 3; ++kh) {
            #pragma unroll
            for (int kw = 0; kw < 3; ++kw) {
                int tap = (ktd * 3 + kh) * 3 + kw;
                int p = kw + m, pm = p & 7;
                #pragma unroll
                for (int chunk = 0; chunk < 2; ++chunk) {
                    short8 a0 = w1v[((tap * 2 + chunk) * 2 + 0) * 64 + lane];
                    short8 a1 = w1v[((tap * 2 + chunk) * 2 + 1) * 64 + lane];
                    int bo = p * 64 + ((((chunk << 2) | q) ^ pm) << 3);
                    #pragma unroll
                    for (int i = 0; i < 2; ++i) {
                        short8 bf = *(const short8*)(lds + (wv * 2 + i + kh) * 1152 + bo);
                        acc[i][0] = MFMA(a0, bf, acc[i][0]);
                        acc[i][1] = MFMA(a1, bf, acc[i][1]);
                    }
                }
            }
        }
    }
    // ---- epilogue: ReLU, store channels-last bf16 bits ----
    int obase = ((b * 16 + t) * 16 + d) * 256 + (h0 + wv * 2) * 16 + m;
    #pragma unroll
    for (int i = 0; i < 2; ++i) {
        int pos = obase + i * 16;
        #pragma unroll
        for (int half = 0; half < 2; ++half) {
            f32x4 v = acc[i][half];
            unsigned r0 = f2bf(fmaxf(v.x, 0.f)), r1 = f2bf(fmaxf(v.y, 0.f));
            unsigned r2 = f2bf(fmaxf(v.z, 0.f)), r3 = f2bf(fmaxf(v.w, 0.f));
            uint2 o;
            o.x = r0 | (r1 << 16);
            o.y = r2 | (r3 << 16);
            *(uint2*)(y1b + (size_t)pos * 32 + half * 16 + q * 4) = o;
        }
    }
}

// ---------------------------------------------------------------------------
// conv2: 3^4 conv Cin=32->Cout=32 on Y1 + fused 1x1 skip (xc, Cin=64) + biases
// + final ReLU -> fp32 output in reference layout [b][co][t][d][h][w].
// Same 4h tile / grid 2048 as conv1.
// ---------------------------------------------------------------------------
__global__ __launch_bounds__(128) void conv2_mfma(const u16* __restrict__ y1b,
                                                  const u16* __restrict__ xcb,
                                                  const u16* __restrict__ w2p,
                                                  const u16* __restrict__ w3p,
                                                  const float* __restrict__ b2,
                                                  const float* __restrict__ b3,
                                                  float* __restrict__ out) {
    __shared__ u16 lds[3456];                    // 6*18*32 = 6.9 KB
    int tid = threadIdx.x;
    int lane = tid & 63, wv = tid >> 6;
    int q = lane >> 4, m = lane & 15;
    int b, t, d, h0;
    decode_bid(blockIdx.x, b, t, d, h0);

    f32x4 acc[2][2];
    {
        float4 p0 = ((const float4*)b2)[q];
        float4 p1 = ((const float4*)b2)[4 + q];
        float4 s0 = ((const float4*)b3)[q];
        float4 s1 = ((const float4*)b3)[4 + q];
        #pragma unroll
        for (int i = 0; i < 2; ++i) {
            acc[i][0] = (f32x4){p0.x + s0.x, p0.y + s0.y, p0.z + s0.z, p0.w + s0.w};
            acc[i][1] = (f32x4){p1.x + s1.x, p1.y + s1.y, p1.z + s1.z, p1.w + s1.w};
        }
    }
    const short8* w2v = (const short8*)w2p;

    for (int ktd = 0; ktd < 9; ++ktd) {
        int kt = ktd / 3, kd = ktd - kt * 3;
        int tt = t + kt - 1, dd = d + kd - 1;
        bool pv = ((unsigned)tt < 16u) && ((unsigned)dd < 16u);
        __syncthreads();
        int pbase = ((b * 16 + tt) * 16 + dd) * 256;
        for (int ui = tid; ui < 432; ui += 128) {    // 6*18*4 16B-units
            int u = ui & 3, p = (ui >> 2) % 18, hh = ui / 72;
            int gh = h0 - 1 + hh, gw = p - 1;
            uint4 val = {0, 0, 0, 0};
            if (pv && (unsigned)gh < 16u && (unsigned)gw < 16u) {
                val = *(const uint4*)(y1b + (size_t)(pbase + gh * 16 + gw) * 32 + u * 8);
            }
            *(uint4*)(lds + hh * 576 + p * 32 + ((u ^ (p & 3)) * 8)) = val;
        }
        __syncthreads();
        #pragma unroll
        for (int kh = 0; kh < 3; ++kh) {
            #pragma unroll
            for (int kw = 0; kw < 3; ++kw) {
                int tap = (ktd * 3 + kh) * 3 + kw;
                int p = kw + m, pm = p & 3;
                short8 a0 = w2v[(tap * 2 + 0) * 64 + lane];
                short8 a1 = w2v[(tap * 2 + 1) * 64 + lane];
                int bo = p * 32 + ((q ^ pm) << 3);
                #pragma unroll
                for (int i = 0; i < 2; ++i) {
                    short8 bf = *(const short8*)(lds + (wv * 2 + i + kh) * 576 + bo);
                    acc[i][0] = MFMA(a0, bf, acc[i][0]);
                    acc[i][1] = MFMA(a1, bf, acc[i][1]);
                }
            }
        }
    }

    // ---- fused 1x1 skip conv from xc (Cin=64, 2 chunks), B direct from global
    const short8* w3v = (const short8*)w3p;
    int lpos0 = ((t * 16 + d) * 256) + (h0 + wv * 2) * 16 + m;   // batch-local pos
    int gpos0 = (b << 16) + lpos0;                               // global pos (ws arrays)
    #pragma unroll
    for (int chunk = 0; chunk < 2; ++chunk) {
        short8 a0 = w3v[(chunk * 2 + 0) * 64 + lane];
        short8 a1 = w3v[(chunk * 2 + 1) * 64 + lane];
        #pragma unroll
        for (int i = 0; i < 2; ++i) {
            short8 bf = *(const short8*)(xcb + (size_t)(gpos0 + i * 16) * 64 + ((chunk << 2) | q) * 8);
            acc[i][0] = MFMA(a0, bf, acc[i][0]);
            acc[i][1] = MFMA(a1, bf, acc[i][1]);
        }
    }

    // ---- epilogue: ReLU, fp32 store to [b][co][local_pos] ----
    #pragma unroll
    for (int i = 0; i < 2; ++i) {
        int lpos = lpos0 + i * 16;
        #pragma unroll
        for (int half = 0; half < 2; ++half) {
            f32x4 v = acc[i][half];
            int co = half * 16 + q * 4;
            float* op = out + (((size_t)(b * 32 + co)) << 16) + lpos;
            op[0ull << 16] = fmaxf(v.x, 0.f);
            op[1ull << 16] = fmaxf(v.y, 0.f);
            op[2ull << 16] = fmaxf(v.z, 0.f);
            op[3ull << 16] = fmaxf(v.w, 0.f);
        }
    }
}

extern "C" void kernel_launch(void* const* d_in, const int* in_sizes, int n_in,
                              void* d_out, int out_size, void* d_ws, size_t ws_size,
                              hipStream_t stream) {
    const float* x1   = (const float*)d_in[0];
    const float* x2   = (const float*)d_in[1];
    const float* up_w = (const float*)d_in[2];
    const float* up_b = (const float*)d_in[3];
    const float* w1   = (const float*)d_in[4];
    const float* b1   = (const float*)d_in[5];
    const float* w2   = (const float*)d_in[6];
    const float* b2   = (const float*)d_in[7];
    const float* w3   = (const float*)d_in[8];
    const float* b3   = (const float*)d_in[9];
    u16* ws  = (u16*)d_ws;
    float* out = (float*)d_out;

    prepack_w<<<1108, 256, 0, stream>>>(w1, w2, w3, up_w, ws);
    xc_copy<<<512, 256, 0, stream>>>(x2, ws + XCB_OFF);
    xc_up<<<16384, 256, 0, stream>>>(x1, (const float*)(ws + UPW_OFF), up_b, ws + XCB_OFF);
    conv1_mfma<<<2048, 128, 0, stream>>>(ws + XCB_OFF, ws + W1P_OFF, b1, ws + Y1B_OFF);
    conv2_mfma<<<2048, 128, 0, stream>>>(ws + Y1B_OFF, ws + XCB_OFF, ws + W2P_OFF,
                                         ws + W3P_OFF, b2, b3, out);
}

// Round 8
// 198.003 us; speedup vs baseline: 7.2004x; 1.2581x over previous
//
#include <hip/hip_runtime.h>

typedef unsigned short u16;
typedef __attribute__((ext_vector_type(8))) short short8;   // 8 bf16 (guide-verified MFMA frag type)
typedef __attribute__((ext_vector_type(4))) float f32x4;

// Workspace layout (u16 element offsets). Total 13,390,848 u16 = 26.8 MB.
#define XCB_OFF  0          // xc  channels-last bf16 [2][16^4][64] = 8,388,608
#define Y1B_OFF  8388608    // Y1  channels-last bf16 [2][16^4][32] = 4,194,304
#define W1P_OFF  12582912   // w1 prepacked [tap81][chunk2][half2][lane64][8] = 165,888
#define W2P_OFF  12748800   // w2 prepacked [tap81][half2][lane64][8]         =  82,944
#define W3P_OFF  12831744   // w3 prepacked [chunk2][half2][lane64][8]        =   2,048
#define UPWP_OFF 12833792   // up_w prepacked [tap16][chunk2][half2][lane64][8] = 32,768
#define X1T_OFF  12866560   // x1 channels-last bf16 [2][4096][64]            = 524,288

__device__ __forceinline__ u16 f2bf(float v) {   // RNE fp32 -> bf16 bits
    unsigned u = __builtin_bit_cast(unsigned, v);
    u += 0x7FFFu + ((u >> 16) & 1u);
    return (u16)(u >> 16);
}

__device__ __forceinline__ f32x4 MFMA(short8 a, short8 b, f32x4 c) {
    return __builtin_amdgcn_mfma_f32_16x16x32_bf16(a, b, c, 0, 0, 0);
}

// bid decode shared by conv kernels: grid 2048 = [b2][t16][d16][hB4],
// arranged so xcd = bid&7 pins each XCD to a t-pair (L2 locality).
__device__ __forceinline__ void decode_bid(int bid, int& b, int& t, int& d, int& h0) {
    int xcd = bid & 7, loc = bid >> 3;
    int hB = loc & 3;
    d = (loc >> 2) & 15;
    int tsub = (loc >> 6) & 1;
    b = loc >> 7;
    t = xcd * 2 + tsub;
    h0 = hB * 4;
}

// ---------------------------------------------------------------------------
// Prepack all conv weights into MFMA A-fragment order (bf16 bits).
// A-frag (16x16x32): a[lane][j] = A[m = lane&15][k = (lane>>4)*8 + j]
// ---------------------------------------------------------------------------
__global__ void prepack_w(const float* __restrict__ w1, const float* __restrict__ w2,
                          const float* __restrict__ w3, const float* __restrict__ upw,
                          u16* __restrict__ ws) {
    int idx = blockIdx.x * 256 + threadIdx.x;
    if (idx < 165888) {
        int j = idx & 7, lane = (idx >> 3) & 63, rest = idx >> 9;
        int half = rest & 1, chunk = (rest >> 1) & 1, tap = rest >> 2;
        int co = half * 16 + (lane & 15), ci = chunk * 32 + (lane >> 4) * 8 + j;
        ws[W1P_OFF + idx] = f2bf(w1[(co * 64 + ci) * 81 + tap]);
    } else if (idx < 165888 + 82944) {
        int i2 = idx - 165888;
        int j = i2 & 7, lane = (i2 >> 3) & 63, rest = i2 >> 9;
        int half = rest & 1, tap = rest >> 1;
        int co = half * 16 + (lane & 15), ci = (lane >> 4) * 8 + j;
        ws[W2P_OFF + i2] = f2bf(w2[(co * 32 + ci) * 81 + tap]);
    } else if (idx < 165888 + 82944 + 2048) {
        int i3 = idx - (165888 + 82944);
        int j = i3 & 7, lane = (i3 >> 3) & 63, rest = i3 >> 9;   // chunk*2+half
        int half = rest & 1, chunk = rest >> 1;
        int co = half * 16 + (lane & 15), ci = chunk * 32 + (lane >> 4) * 8 + j;
        ws[W3P_OFF + i3] = f2bf(w3[co * 64 + ci]);
    } else if (idx < 250880 + 32768) {
        int i4 = idx - 250880;                        // [tap][chunk][half][lane][8]
        int j = i4 & 7, lane = (i4 >> 3) & 63, rest = i4 >> 9;
        int half = rest & 1, chunk = (rest >> 1) & 1, tap = rest >> 2;
        int co = half * 16 + (lane & 15), ci = chunk * 32 + (lane >> 4) * 8 + j;
        ws[UPWP_OFF + i4] = f2bf(upw[(ci * 32 + co) * 16 + tap]);   // [Cin][Cout][taps]
    }
}

// ---------------------------------------------------------------------------
// xc_copy: x2 (channel-major fp32) -> xcb channels 0..31 (channels-last bf16)
// via padded-LDS tile transpose. Block = 256 thr, tile = 256 pos x 32 c.
// ---------------------------------------------------------------------------
__global__ __launch_bounds__(256) void xc_copy(const float* __restrict__ x2,
                                               u16* __restrict__ xcb) {
    __shared__ u16 lds[256 * 34];                // pad 34: conflict-free transpose
    int tid = threadIdx.x;
    int b = blockIdx.x >> 8;
    int pos_base = (blockIdx.x & 255) * 256;
    #pragma unroll
    for (int c = 0; c < 32; ++c) {               // coalesced 1KB reads per c-row
        lds[tid * 34 + c] = f2bf(x2[((b * 32 + c) << 16) + pos_base + tid]);
    }
    __syncthreads();
    #pragma unroll
    for (int k = 0; k < 32; ++k) {               // c-major stores
        int f = k * 256 + tid;
        int c = f & 31, pos = f >> 5;
        xcb[(size_t)((b << 16) + pos_base + pos) * 64 + c] = lds[pos * 34 + c];
    }
}

// ---------------------------------------------------------------------------
// x1_tr: x1 (channel-major fp32 [2][64][4096]) -> x1t (channels-last bf16
// [2][4096][64]) via padded-LDS transpose. 32 blocks.
// ---------------------------------------------------------------------------
__global__ __launch_bounds__(256) void x1_tr(const float* __restrict__ x1,
                                             u16* __restrict__ x1t) {
    __shared__ u16 lds[256 * 66];                // pad 66: conflict-free
    int tid = threadIdx.x;
    int b = blockIdx.x >> 4;
    int pos_base = (blockIdx.x & 15) * 256;
    #pragma unroll
    for (int c = 0; c < 64; ++c) {
        lds[tid * 66 + c] = f2bf(x1[((b * 64 + c) << 12) + pos_base + tid]);
    }
    __syncthreads();
    #pragma unroll
    for (int k = 0; k < 64; ++k) {
        int f = k * 256 + tid;
        int ci = f & 63, pos = f >> 6;
        x1t[(size_t)((b << 12) + pos_base + pos) * 64 + ci] = lds[pos * 66 + ci];
    }
}

// ---------------------------------------------------------------------------
// xc_up_mfma: tconv4d(k2,s2) as 32 per-(b,tap) GEMMs [4096 ipos x 32 co, K=64].
// One wave = 64 ipos x 32 co = 16 MFMAs; B-frags straight from global x1t
// (contiguous 16 B/lane); bias in acc init; writes xcb channels 32..63.
// 2048 waves total (512 blocks x 4).
// ---------------------------------------------------------------------------
__global__ __launch_bounds__(256) void xc_up_mfma(const u16* __restrict__ x1t,
                                                  const u16* __restrict__ upwp,
                                                  const float* __restrict__ up_b,
                                                  u16* __restrict__ xcb) {
    int tid = threadIdx.x;
    int wv = tid >> 6, lane = tid & 63;
    int q = lane >> 4, m = lane & 15;
    int wid = blockIdx.x * 4 + wv;               // [b2][tap16][j64]
    int j = wid & 63, tap = (wid >> 6) & 15, b = wid >> 10;

    f32x4 acc[4][2];
    {
        float4 bi0 = ((const float4*)up_b)[q];       // co = q*4+r
        float4 bi1 = ((const float4*)up_b)[4 + q];   // co = 16+q*4+r
        #pragma unroll
        for (int g = 0; g < 4; ++g) {
            acc[g][0] = (f32x4){bi0.x, bi0.y, bi0.z, bi0.w};
            acc[g][1] = (f32x4){bi1.x, bi1.y, bi1.z, bi1.w};
        }
    }

    const short8* wv8 = (const short8*)upwp;
    const u16* xb = x1t + (size_t)((b << 12) + (j << 6) + m) * 64;   // + (g*16)*64
    #pragma unroll
    for (int chunk = 0; chunk < 2; ++chunk) {
        short8 a0 = wv8[((tap * 2 + chunk) * 2 + 0) * 64 + lane];
        short8 a1 = wv8[((tap * 2 + chunk) * 2 + 1) * 64 + lane];
        #pragma unroll
        for (int g = 0; g < 4; ++g) {
            short8 bf = *(const short8*)(xb + (size_t)(g * 16) * 64 + chunk * 32 + q * 8);
            acc[g][0] = MFMA(a0, bf, acc[g][0]);
            acc[g][1] = MFMA(a1, bf, acc[g][1]);
        }
    }

    // epilogue: C/D col = ipos-local (lane&15), row = co-in-half = q*4+r.
    int it = j >> 3, id = j & 7;
    int pt = tap >> 3, pd = (tap >> 2) & 1, ph = (tap >> 1) & 1, pw = tap & 1;
    int oT = 2 * it + pt, oD = 2 * id + pd, oW = 2 * (m & 7) + pw;
    #pragma unroll
    for (int g = 0; g < 4; ++g) {
        int ih = g * 2 + (m >> 3);
        int opos = oT * 4096 + oD * 256 + (2 * ih + ph) * 16 + oW;
        u16* op = xcb + (size_t)((b << 16) + opos) * 64 + 32 + q * 4;
        #pragma unroll
        for (int half = 0; half < 2; ++half) {
            f32x4 v = acc[g][half];
            uint2 o;
            o.x = (unsigned)f2bf(v.x) | ((unsigned)f2bf(v.y) << 16);
            o.y = (unsigned)f2bf(v.z) | ((unsigned)f2bf(v.w) << 16);
            *(uint2*)(op + half * 16) = o;
        }
    }
}

// ---------------------------------------------------------------------------
// conv1: 3^4 conv, Cin=64 -> Cout=32, pad 1, +bias +ReLU -> Y1 (channels-last
// bf16). Block=128thr(2 waves): tile 4h x 16w x 32co at fixed (b,t,d).
// LDS: one (tt,dd) halo plane 6h' x 18w' x 64ci, 16B-unit XOR swizzle.
// ---------------------------------------------------------------------------
__global__ __launch_bounds__(128) void conv1_mfma(const u16* __restrict__ xcb,
                                                  const u16* __restrict__ w1p,
                                                  const float* __restrict__ b1,
                                                  u16* __restrict__ y1b) {
    __shared__ u16 lds[6912];                    // 6*18*64 = 13.8 KB
    int tid = threadIdx.x;
    int lane = tid & 63, wv = tid >> 6;
    int q = lane >> 4, m = lane & 15;
    int b, t, d, h0;
    decode_bid(blockIdx.x, b, t, d, h0);

    f32x4 acc[2][2];
    {
        float4 bi0 = ((const float4*)b1)[q];
        float4 bi1 = ((const float4*)b1)[4 + q];
        #pragma unroll
        for (int i = 0; i < 2; ++i) {
            acc[i][0] = (f32x4){bi0.x, bi0.y, bi0.z, bi0.w};
            acc[i][1] = (f32x4){bi1.x, bi1.y, bi1.z, bi1.w};
        }
    }
    const short8* w1v = (const short8*)w1p;

    for (int ktd = 0; ktd < 9; ++ktd) {
        int kt = ktd / 3, kd = ktd - kt * 3;
        int tt = t + kt - 1, dd = d + kd - 1;
        bool pv = ((unsigned)tt < 16u) && ((unsigned)dd < 16u);
        __syncthreads();
        int pbase = ((b * 16 + tt) * 16 + dd) * 256;
        for (int ui = tid; ui < 864; ui += 128) {    // 6*18*8 16B-units
            int u = ui & 7, p = (ui >> 3) % 18, hh = ui / 144;
            int gh = h0 - 1 + hh, gw = p - 1;
            uint4 val = {0, 0, 0, 0};
            if (pv && (unsigned)gh < 16u && (unsigned)gw < 16u) {
                val = *(const uint4*)(xcb + (size_t)(pbase + gh * 16 + gw) * 64 + u * 8);
            }
            *(uint4*)(lds + hh * 1152 + p * 64 + ((u ^ (p & 7)) * 8)) = val;
        }
        __syncthreads();
        #pragma unroll
        for (int kh = 0; kh < 3; ++kh) {
            #pragma unroll
            for (int kw = 0; kw < 3; ++kw) {
                int tap = (ktd * 3 + kh) * 3 + kw;
                int p = kw + m, pm = p & 7;
                #pragma unroll
                for (int chunk = 0; chunk < 2; ++chunk) {
                    short8 a0 = w1v[((tap * 2 + chunk) * 2 + 0) * 64 + lane];
                    short8 a1 = w1v[((tap * 2 + chunk) * 2 + 1) * 64 + lane];
                    int bo = p * 64 + ((((chunk << 2) | q) ^ pm) << 3);
                    #pragma unroll
                    for (int i = 0; i < 2; ++i) {
                        short8 bf = *(const short8*)(lds + (wv * 2 + i + kh) * 1152 + bo);
                        acc[i][0] = MFMA(a0, bf, acc[i][0]);
                        acc[i][1] = MFMA(a1, bf, acc[i][1]);
                    }
                }
            }
        }
    }
    int obase = ((b * 16 + t) * 16 + d) * 256 + (h0 + wv * 2) * 16 + m;
    #pragma unroll
    for (int i = 0; i < 2; ++i) {
        int pos = obase + i * 16;
        #pragma unroll
        for (int half = 0; half < 2; ++half) {
            f32x4 v = acc[i][half];
            unsigned r0 = f2bf(fmaxf(v.x, 0.f)), r1 = f2bf(fmaxf(v.y, 0.f));
            unsigned r2 = f2bf(fmaxf(v.z, 0.f)), r3 = f2bf(fmaxf(v.w, 0.f));
            uint2 o;
            o.x = r0 | (r1 << 16);
            o.y = r2 | (r3 << 16);
            *(uint2*)(y1b + (size_t)pos * 32 + half * 16 + q * 4) = o;
        }
    }
}

// ---------------------------------------------------------------------------
// conv2: 3^4 conv Cin=32->Cout=32 on Y1 + fused 1x1 skip (xc, Cin=64) + biases
// + final ReLU -> fp32 output in reference layout [b][co][t][d][h][w].
// ---------------------------------------------------------------------------
__global__ __launch_bounds__(128) void conv2_mfma(const u16* __restrict__ y1b,
                                                  const u16* __restrict__ xcb,
                                                  const u16* __restrict__ w2p,
                                                  const u16* __restrict__ w3p,
                                                  const float* __restrict__ b2,
                                                  const float* __restrict__ b3,
                                                  float* __restrict__ out) {
    __shared__ u16 lds[3456];                    // 6*18*32 = 6.9 KB
    int tid = threadIdx.x;
    int lane = tid & 63, wv = tid >> 6;
    int q = lane >> 4, m = lane & 15;
    int b, t, d, h0;
    decode_bid(blockIdx.x, b, t, d, h0);

    f32x4 acc[2][2];
    {
        float4 p0 = ((const float4*)b2)[q];
        float4 p1 = ((const float4*)b2)[4 + q];
        float4 s0 = ((const float4*)b3)[q];
        float4 s1 = ((const float4*)b3)[4 + q];
        #pragma unroll
        for (int i = 0; i < 2; ++i) {
            acc[i][0] = (f32x4){p0.x + s0.x, p0.y + s0.y, p0.z + s0.z, p0.w + s0.w};
            acc[i][1] = (f32x4){p1.x + s1.x, p1.y + s1.y, p1.z + s1.z, p1.w + s1.w};
        }
    }
    const short8* w2v = (const short8*)w2p;

    for (int ktd = 0; ktd < 9; ++ktd) {
        int kt = ktd / 3, kd = ktd - kt * 3;
        int tt = t + kt - 1, dd = d + kd - 1;
        bool pv = ((unsigned)tt < 16u) && ((unsigned)dd < 16u);
        __syncthreads();
        int pbase = ((b * 16 + tt) * 16 + dd) * 256;
        for (int ui = tid; ui < 432; ui += 128) {    // 6*18*4 16B-units
            int u = ui & 3, p = (ui >> 2) % 18, hh = ui / 72;
            int gh = h0 - 1 + hh, gw = p - 1;
            uint4 val = {0, 0, 0, 0};
            if (pv && (unsigned)gh < 16u && (unsigned)gw < 16u) {
                val = *(const uint4*)(y1b + (size_t)(pbase + gh * 16 + gw) * 32 + u * 8);
            }
            *(uint4*)(lds + hh * 576 + p * 32 + ((u ^ (p & 3)) * 8)) = val;
        }
        __syncthreads();
        #pragma unroll
        for (int kh = 0; kh < 3; ++kh) {
            #pragma unroll
            for (int kw = 0; kw < 3; ++kw) {
                int tap = (ktd * 3 + kh) * 3 + kw;
                int p = kw + m, pm = p & 3;
                short8 a0 = w2v[(tap * 2 + 0) * 64 + lane];
                short8 a1 = w2v[(tap * 2 + 1) * 64 + lane];
                int bo = p * 32 + ((q ^ pm) << 3);
                #pragma unroll
                for (int i = 0; i < 2; ++i) {
                    short8 bf = *(const short8*)(lds + (wv * 2 + i + kh) * 576 + bo);
                    acc[i][0] = MFMA(a0, bf, acc[i][0]);
                    acc[i][1] = MFMA(a1, bf, acc[i][1]);
                }
            }
        }
    }

    const short8* w3v = (const short8*)w3p;
    int lpos0 = ((t * 16 + d) * 256) + (h0 + wv * 2) * 16 + m;   // batch-local pos
    int gpos0 = (b << 16) + lpos0;                               // global pos (ws arrays)
    #pragma unroll
    for (int chunk = 0; chunk < 2; ++chunk) {
        short8 a0 = w3v[(chunk * 2 + 0) * 64 + lane];
        short8 a1 = w3v[(chunk * 2 + 1) * 64 + lane];
        #pragma unroll
        for (int i = 0; i < 2; ++i) {
            short8 bf = *(const short8*)(xcb + (size_t)(gpos0 + i * 16) * 64 + ((chunk << 2) | q) * 8);
            acc[i][0] = MFMA(a0, bf, acc[i][0]);
            acc[i][1] = MFMA(a1, bf, acc[i][1]);
        }
    }

    #pragma unroll
    for (int i = 0; i < 2; ++i) {
        int lpos = lpos0 + i * 16;
        #pragma unroll
        for (int half = 0; half < 2; ++half) {
            f32x4 v = acc[i][half];
            int co = half * 16 + q * 4;
            float* op = out + (((size_t)(b * 32 + co)) << 16) + lpos;
            op[0ull << 16] = fmaxf(v.x, 0.f);
            op[1ull << 16] = fmaxf(v.y, 0.f);
            op[2ull << 16] = fmaxf(v.z, 0.f);
            op[3ull << 16] = fmaxf(v.w, 0.f);
        }
    }
}

extern "C" void kernel_launch(void* const* d_in, const int* in_sizes, int n_in,
                              void* d_out, int out_size, void* d_ws, size_t ws_size,
                              hipStream_t stream) {
    const float* x1   = (const float*)d_in[0];
    const float* x2   = (const float*)d_in[1];
    const float* up_w = (const float*)d_in[2];
    const float* up_b = (const float*)d_in[3];
    const float* w1   = (const float*)d_in[4];
    const float* b1   = (const float*)d_in[5];
    const float* w2   = (const float*)d_in[6];
    const float* b2   = (const float*)d_in[7];
    const float* w3   = (const float*)d_in[8];
    const float* b3   = (const float*)d_in[9];
    u16* ws  = (u16*)d_ws;
    float* out = (float*)d_out;

    prepack_w<<<1108, 256, 0, stream>>>(w1, w2, w3, up_w, ws);
    xc_copy<<<512, 256, 0, stream>>>(x2, ws + XCB_OFF);
    x1_tr<<<32, 256, 0, stream>>>(x1, ws + X1T_OFF);
    xc_up_mfma<<<512, 256, 0, stream>>>(ws + X1T_OFF, ws + UPWP_OFF, up_b, ws + XCB_OFF);
    conv1_mfma<<<2048, 128, 0, stream>>>(ws + XCB_OFF, ws + W1P_OFF, b1, ws + Y1B_OFF);
    conv2_mfma<<<2048, 128, 0, stream>>>(ws + Y1B_OFF, ws + XCB_OFF, ws + W2P_OFF,
                                         ws + W3P_OFF, b2, b3, out);
}